// Round 7
// baseline (731.778 us; speedup 1.0000x reference)
//
#include <hip/hip_runtime.h>
#include <hip/hip_fp16.h>

#define BB 64
#define NN 4096
#define MM 128
#define SCALE 0.25f
#define NC 2              // n rows per LDS chunk

typedef const __attribute__((address_space(1))) void* gp_t;
typedef __attribute__((address_space(3))) void* lp_t;

// Block: BGRP waves, wave i owns b = bgrp*BGRP+i; all waves share LDS-staged
// w rows (reuse = BGRP). Lane l owns m = 2l, 2l+1.
// EPI=0: store fp16 partials part[nsplit][b][k][m] (plain stores, no RMW).
// EPI=1: fp32 atomics into acc[b][k][m] via contiguous-lane transpose.
template <int BGRP, int NSPLIT, int EPI>
__global__ __launch_bounds__(BGRP * 64) void caps_fused(
        const float* __restrict__ x, const float* __restrict__ ncv,
        const float* __restrict__ w, void* __restrict__ outp) {
    static_assert(NC == 2, "pose-staging math assumes NC==2");
    constexpr int NR = NN / NSPLIT;
    constexpr int CHUNKS = NR / NC;
    constexpr int JW = (NC * 2048) / (BGRP * 256);  // w-stage instr per wave
    const int nsplit = blockIdx.x % NSPLIT;
    const int bgrp   = blockIdx.x / NSPLIT;
    const int wave   = threadIdx.x >> 6;
    const int lane   = threadIdx.x & 63;
    const int b      = bgrp * BGRP + wave;
    const int n0     = nsplit * NR;
    const int m0     = lane * 2;

    __shared__ float lds_w[2][NC * 2048];       // 2 x 16 KB
    __shared__ float lds_p[2][BGRP * NC * 16];

    // ncv[b, m0, :], ncv[b, m0+1, :]
    float nc0[16], nc1[16];
    {
        const float4* p0 = (const float4*)(ncv + ((size_t)b * MM + m0) * 16);
        const float4* p1 = (const float4*)(ncv + ((size_t)b * MM + m0 + 1) * 16);
#pragma unroll
        for (int i = 0; i < 4; ++i) {
            float4 t = p0[i];
            nc0[4 * i + 0] = t.x; nc0[4 * i + 1] = t.y; nc0[4 * i + 2] = t.z; nc0[4 * i + 3] = t.w;
            float4 u = p1[i];
            nc1[4 * i + 0] = u.x; nc1[4 * i + 1] = u.y; nc1[4 * i + 2] = u.z; nc1[4 * i + 3] = u.w;
        }
    }

    float oa0[16], oa1[16];
#pragma unroll
    for (int k = 0; k < 16; ++k) { oa0[k] = 0.0f; oa1[k] = 0.0f; }

    auto stage = [&](int c, int buf) {
        const float* wsrc = w + (size_t)(n0 + c * NC) * 2048;
#pragma unroll
        for (int j = 0; j < JW; ++j) {
            const int off = (wave * JW + j) * 256;   // floats; uniform per wave
            __builtin_amdgcn_global_load_lds((gp_t)(wsrc + off + lane * 4),
                                             (lp_t)(&lds_w[buf][off]), 16, 0, 0);
        }
        // pose for all BGRP b's of this chunk: slot s -> b'=s/8, quad q=s%8
        if (wave == 0) {
            constexpr int S = BGRP * NC * 4;   // float4 slots
#pragma unroll
            for (int s0 = 0; s0 < S; s0 += 64) {
                const int s = s0 + lane;
                const int bp = s >> 3, q = s & 7;
                const float* psrc = x + ((size_t)(bgrp * BGRP + bp) * NN + n0 + c * NC) * 16 + q * 4;
                __builtin_amdgcn_global_load_lds((gp_t)psrc,
                                                 (lp_t)(&lds_p[buf][s0 * 4]), 16, 0, 0);
            }
        }
    };

    stage(0, 0);
    __syncthreads();

    for (int c = 0; c < CHUNKS; ++c) {
        const int buf = c & 1;
        if (c + 1 < CHUNKS) stage(c + 1, buf ^ 1);
#pragma unroll
        for (int nn = 0; nn < NC; ++nn) {
            const float* wrow = &lds_w[buf][nn * 2048 + m0];
            const float* pt   = &lds_p[buf][wave * (NC * 16) + nn * 16];
            float4 pA = *(const float4*)(pt + 0);
            float4 pB = *(const float4*)(pt + 4);
            float4 pC = *(const float4*)(pt + 8);
            float4 pD = *(const float4*)(pt + 12);
            // votes v[a*4+d] = sum_x pose[a][x] * w[x*4+d]
            float v0[16], v1[16];
#pragma unroll
            for (int d = 0; d < 4; ++d) {
                float2 w0 = *(const float2*)(wrow + (0 * 4 + d) * 128);
                float2 w1 = *(const float2*)(wrow + (1 * 4 + d) * 128);
                float2 w2 = *(const float2*)(wrow + (2 * 4 + d) * 128);
                float2 w3 = *(const float2*)(wrow + (3 * 4 + d) * 128);
                v0[0  + d] = fmaf(pA.x, w0.x, fmaf(pA.y, w1.x, fmaf(pA.z, w2.x, pA.w * w3.x)));
                v1[0  + d] = fmaf(pA.x, w0.y, fmaf(pA.y, w1.y, fmaf(pA.z, w2.y, pA.w * w3.y)));
                v0[4  + d] = fmaf(pB.x, w0.x, fmaf(pB.y, w1.x, fmaf(pB.z, w2.x, pB.w * w3.x)));
                v1[4  + d] = fmaf(pB.x, w0.y, fmaf(pB.y, w1.y, fmaf(pB.z, w2.y, pB.w * w3.y)));
                v0[8  + d] = fmaf(pC.x, w0.x, fmaf(pC.y, w1.x, fmaf(pC.z, w2.x, pC.w * w3.x)));
                v1[8  + d] = fmaf(pC.x, w0.y, fmaf(pC.y, w1.y, fmaf(pC.z, w2.y, pC.w * w3.y)));
                v0[12 + d] = fmaf(pD.x, w0.x, fmaf(pD.y, w1.x, fmaf(pD.z, w2.x, pD.w * w3.x)));
                v1[12 + d] = fmaf(pD.x, w0.y, fmaf(pD.y, w1.y, fmaf(pD.z, w2.y, pD.w * w3.y)));
            }
            // qk = SCALE * <v, nc>
            float qk0 = 0.0f, qk1 = 0.0f;
#pragma unroll
            for (int k = 0; k < 16; ++k) {
                qk0 = fmaf(v0[k], nc0[k], qk0);
                qk1 = fmaf(v1[k], nc1[k], qk1);
            }
            // softmax over 128 m (2/lane); |qk*SCALE| small -> no max-subtract.
            float p0 = __expf(qk0 * SCALE), p1 = __expf(qk1 * SCALE);
            float s = p0 + p1;
#pragma unroll
            for (int off = 32; off; off >>= 1) s += __shfl_xor(s, off);
            float rinv = 1.0f / s;
            float r0 = p0 * rinv, r1 = p1 * rinv;
#pragma unroll
            for (int k = 0; k < 16; ++k) {
                oa0[k] = fmaf(r0, v0[k], oa0[k]);
                oa1[k] = fmaf(r1, v1[k], oa1[k]);
            }
        }
        __syncthreads();
    }

    if constexpr (EPI == 0) {
        // fp16 partials: half2 store at (k*128 + 2l)/2 -> 256B contiguous/instr
        __half2* part = (__half2*)outp;
        const size_t base2 = ((size_t)nsplit * BB + b) * (16 * MM / 2);
#pragma unroll
        for (int k = 0; k < 16; ++k)
            part[base2 + k * 64 + lane] = __floats2half2_rn(oa0[k], oa1[k]);
    } else {
        // lane transpose: lane l -> m=l and m=64+l, then contiguous-lane atomics
        float na[16], nb[16];
        const int src0 = lane >> 1;
        const int src1 = 32 + (lane >> 1);
        const bool odd = lane & 1;
#pragma unroll
        for (int k = 0; k < 16; ++k) {
            float a0 = __shfl(oa0[k], src0);
            float a1 = __shfl(oa1[k], src0);
            float b0 = __shfl(oa0[k], src1);
            float b1 = __shfl(oa1[k], src1);
            na[k] = odd ? a1 : a0;
            nb[k] = odd ? b1 : b0;
        }
        float* gout = (float*)outp + (size_t)b * (16 * MM);
#pragma unroll
        for (int k = 0; k < 16; ++k) {
            atomicAdd(gout + k * MM + lane,      na[k]);
            atomicAdd(gout + k * MM + 64 + lane, nb[k]);
        }
    }
}

// Block per b: sum fp16 partials over NSPLIT (coalesced), LN, write out.
template <int NSPLIT>
__global__ __launch_bounds__(256) void caps_reduce_ln(const __half2* __restrict__ part,
                                                      const float* __restrict__ gamma,
                                                      const float* __restrict__ beta,
                                                      float* __restrict__ out) {
    const int b = blockIdx.x;
    const int t = threadIdx.x;            // 256 threads x 8 elements
    __shared__ float lds[16 * MM];
    float s[8];
#pragma unroll
    for (int i = 0; i < 8; ++i) s[i] = 0.0f;
    const __half2* p = part + (size_t)b * 1024 + t * 4;
    for (int ns = 0; ns < NSPLIT; ++ns) {
        const __half2* q = p + (size_t)ns * (BB * 1024);
#pragma unroll
        for (int i = 0; i < 4; ++i) {
            float2 f = __half22float2(q[i]);
            s[2 * i]     += f.x;
            s[2 * i + 1] += f.y;
        }
    }
#pragma unroll
    for (int i = 0; i < 8; ++i) lds[t * 8 + i] = s[i];
    __syncthreads();
    if (t < MM) {                         // t = m ; lds layout [k][m]
        float v[16];
        float mu = 0.0f;
#pragma unroll
        for (int k = 0; k < 16; ++k) { v[k] = lds[k * MM + t]; mu += v[k]; }
        mu *= (1.0f / 16.0f);
        float var = 0.0f;
#pragma unroll
        for (int k = 0; k < 16; ++k) { float d = v[k] - mu; var = fmaf(d, d, var); }
        var *= (1.0f / 16.0f);
        float rs = rsqrtf(var + 1e-5f);
        float4* o = (float4*)(out + ((size_t)b * MM + t) * 16);
#pragma unroll
        for (int i = 0; i < 4; ++i) {
            float4 r;
            r.x = (v[4 * i + 0] - mu) * rs * gamma[4 * i + 0] + beta[4 * i + 0];
            r.y = (v[4 * i + 1] - mu) * rs * gamma[4 * i + 1] + beta[4 * i + 1];
            r.z = (v[4 * i + 2] - mu) * rs * gamma[4 * i + 2] + beta[4 * i + 2];
            r.w = (v[4 * i + 3] - mu) * rs * gamma[4 * i + 3] + beta[4 * i + 3];
            o[i] = r;
        }
    }
}

// Fallback LN over fp32 acc[b][k][m].
__global__ __launch_bounds__(128) void caps_ln(const float* __restrict__ acc,
                                               const float* __restrict__ gamma,
                                               const float* __restrict__ beta,
                                               float* __restrict__ out) {
    const int b = blockIdx.x;
    const int t = threadIdx.x;   // = m
    __shared__ float lds[16 * MM];
    const float* gacc = acc + (size_t)b * (16 * MM);
#pragma unroll
    for (int j = 0; j < 4; ++j) {
        const int idx = j * 512 + t * 4;
        *(float4*)(lds + idx) = *(const float4*)(gacc + idx);
    }
    __syncthreads();
    float v[16];
    float mu = 0.0f;
#pragma unroll
    for (int k = 0; k < 16; ++k) { v[k] = lds[k * MM + t]; mu += v[k]; }
    mu *= (1.0f / 16.0f);
    float var = 0.0f;
#pragma unroll
    for (int k = 0; k < 16; ++k) { float d = v[k] - mu; var = fmaf(d, d, var); }
    var *= (1.0f / 16.0f);
    float rs = rsqrtf(var + 1e-5f);
    float4* o = (float4*)(out + ((size_t)b * MM + t) * 16);
#pragma unroll
    for (int i = 0; i < 4; ++i) {
        float4 r;
        r.x = (v[4 * i + 0] - mu) * rs * gamma[4 * i + 0] + beta[4 * i + 0];
        r.y = (v[4 * i + 1] - mu) * rs * gamma[4 * i + 1] + beta[4 * i + 1];
        r.z = (v[4 * i + 2] - mu) * rs * gamma[4 * i + 2] + beta[4 * i + 2];
        r.w = (v[4 * i + 3] - mu) * rs * gamma[4 * i + 3] + beta[4 * i + 3];
        o[i] = r;
    }
}

extern "C" void kernel_launch(void* const* d_in, const int* in_sizes, int n_in,
                              void* d_out, int out_size, void* d_ws, size_t ws_size,
                              hipStream_t stream) {
    const float* x     = (const float*)d_in[0];
    const float* ncv   = (const float*)d_in[1];
    const float* w     = (const float*)d_in[2];
    const float* gamma = (const float*)d_in[3];
    const float* beta  = (const float*)d_in[4];
    float* out = (float*)d_out;

    const size_t need_fp16 = (size_t)64 * BB * 16 * MM * sizeof(__half);  // 16 MB

    if (ws_size >= need_fp16) {
        // zero-atomic path: BGRP=16 (16x w reuse, 4 waves/SIMD), NSPLIT=64
        caps_fused<16, 64, 0><<<dim3((BB / 16) * 64), 1024, 0, stream>>>(x, ncv, w, d_ws);
        caps_reduce_ln<64><<<BB, 256, 0, stream>>>((const __half2*)d_ws, gamma, beta, out);
    } else {
        // atomic fallback: NSPLIT=32 (1/4 of R6's atomic bursts), 512 KiB acc
        hipMemsetAsync(d_ws, 0, (size_t)BB * 16 * MM * sizeof(float), stream);
        caps_fused<8, 32, 1><<<dim3((BB / 8) * 32), 512, 0, stream>>>(x, ncv, w, d_ws);
        caps_ln<<<BB, 128, 0, stream>>>((const float*)d_ws, gamma, beta, out);
    }
}